// Round 2
// baseline (2212.233 us; speedup 1.0000x reference)
//
#include <hip/hip_runtime.h>
#include <math.h>
#include <cstdint>
#include <cstddef>

// B=2, T=1024, C=4096, H=32, G=8, D=128, rep=4, M=B*T=2048
typedef __bf16 bf16_t;
typedef __bf16 bf16x8 __attribute__((ext_vector_type(8)));
typedef __bf16 bf16x4 __attribute__((ext_vector_type(4)));
typedef float f32x4 __attribute__((ext_vector_type(4)));
typedef float f32x16 __attribute__((ext_vector_type(16)));

#define MFMA16(a, b, c) __builtin_amdgcn_mfma_f32_16x16x32_bf16(a, b, c, 0, 0, 0)
#define MFMA32(a, b, c) __builtin_amdgcn_mfma_f32_32x32x16_bf16(a, b, c, 0, 0, 0)

__device__ __forceinline__ void stage16(const void* g, void* l) {
  __builtin_amdgcn_global_load_lds(
      (const __attribute__((address_space(1))) unsigned int*)g,
      (__attribute__((address_space(3))) unsigned int*)l, 16, 0, 0);
}

__device__ __forceinline__ bf16x4 shfl_xor32_b64(bf16x4 v) {
  union { bf16x4 h; unsigned int u[2]; } a;
  a.h = v;
  a.u[0] = __shfl_xor(a.u[0], 32);
  a.u[1] = __shfl_xor(a.u[1], 32);
  return a.h;
}

__device__ __forceinline__ bf16x8 cat44(bf16x4 lo, bf16x4 hiv) {
  bf16x8 r;
  r[0] = lo[0]; r[1] = lo[1]; r[2] = lo[2]; r[3] = lo[3];
  r[4] = hiv[0]; r[5] = hiv[1]; r[6] = hiv[2]; r[7] = hiv[3];
  return r;
}

// ---------------- convert fp32 -> bf16 ----------------
__global__ void k_convert(const float* __restrict__ in, bf16_t* __restrict__ out, int n) {
  int i = (blockIdx.x * blockDim.x + threadIdx.x) * 4;
  if (i >= n) return;
  float4 v = *(const float4*)(in + i);
  out[i + 0] = (bf16_t)v.x;
  out[i + 1] = (bf16_t)v.y;
  out[i + 2] = (bf16_t)v.z;
  out[i + 3] = (bf16_t)v.w;
}

// ---------------- transpose+convert: out[c][r] = in[r][c] ----------------
__global__ void k_transpose(const float* __restrict__ in, bf16_t* __restrict__ out,
                            int R, int C) {
  __shared__ float t[32][33];
  int r0 = blockIdx.y * 32, c0 = blockIdx.x * 32;
  int tx = threadIdx.x, ty = threadIdx.y;
#pragma unroll
  for (int i = 0; i < 4; i++)
    t[ty + i * 8][tx] = in[(size_t)(r0 + ty + i * 8) * C + (c0 + tx)];
  __syncthreads();
#pragma unroll
  for (int i = 0; i < 4; i++)
    out[(size_t)(c0 + ty + i * 8) * R + (r0 + tx)] = (bf16_t)t[tx][ty + i * 8];
}

// ---------------- GEMM: 128x128 tile, BK=32, m97 structure -----------------------
// MODE 0: Cout = A*BT^T + bias (fp32 out)
// MODE 1: fused QKV epilogue: n0<4096 -> Q(rope,scale)->Qb [B][H][T][128]
//         4096<=n0<5120 -> K(rope)->Kb [B][G][T][128]; n0>=5120 -> V->Vt [B][G][128][T]
template <int MODE>
__global__ __launch_bounds__(256) void k_gemm(
    const bf16_t* __restrict__ A, const bf16_t* __restrict__ BT,
    float* __restrict__ Cout, const float* __restrict__ bias,
    bf16_t* __restrict__ Qb, bf16_t* __restrict__ Kb, bf16_t* __restrict__ Vt,
    int M, int N, int K) {
  __shared__ __align__(16) bf16_t As[128 * 32];
  __shared__ __align__(16) bf16_t Bs[128 * 32];
  int tid = threadIdx.x;
  int w = tid >> 6, lane = tid & 63, quad = lane >> 4, l16 = lane & 15;
  int n0 = blockIdx.x * 128, m0 = blockIdx.y * 128;
  int wm = (w >> 1) * 64, wn = (w & 1) * 64;
  const char* Ab = (const char*)A + (size_t)m0 * K * 2;
  const char* Bb = (const char*)BT + (size_t)n0 * K * 2;
  size_t rb = (size_t)K * 2;
  f32x4 acc[4][4] = {};
  for (int k0 = 0; k0 < K; k0 += 32) {
    __syncthreads();
#pragma unroll
    for (int it = 0; it < 2; ++it) {
      int off = it * 4096 + tid * 16;
      int row = off >> 6;
      int colb = off & 63;
      stage16(Ab + (size_t)row * rb + (size_t)k0 * 2 + colb, (char*)As + off);
      stage16(Bb + (size_t)row * rb + (size_t)k0 * 2 + colb, (char*)Bs + off);
    }
    __syncthreads();
    bf16x8 af[4], bfr[4];
#pragma unroll
    for (int i = 0; i < 4; i++)
      af[i] = *(const bf16x8*)&As[(wm + i * 16 + l16) * 32 + quad * 8];
#pragma unroll
    for (int j = 0; j < 4; j++)
      bfr[j] = *(const bf16x8*)&Bs[(wn + j * 16 + l16) * 32 + quad * 8];
#pragma unroll
    for (int i = 0; i < 4; i++)
#pragma unroll
      for (int j = 0; j < 4; j++)
        acc[i][j] = MFMA16(af[i], bfr[j], acc[i][j]);
  }

  if (MODE == 0) {
#pragma unroll
    for (int i = 0; i < 4; i++)
#pragma unroll
      for (int j = 0; j < 4; j++) {
        int col = n0 + wn + j * 16 + l16;
        float bv = bias[col];
#pragma unroll
        for (int r = 0; r < 4; r++) {
          int row = m0 + wm + i * 16 + quad * 4 + r;
          Cout[(size_t)row * N + col] = acc[i][j][r] + bv;
        }
      }
  } else {
    if (n0 < 5120) {
      // rope path (Q or K)
      bf16_t* dst;
      int NH, cbase;
      float scale;
      if (n0 < 4096) { dst = Qb; NH = 32; cbase = 0; scale = 0.08838834764831845f; }
      else           { dst = Kb; NH = 8;  cbase = 4096; scale = 1.0f; }
      int par = l16 & 1;
#pragma unroll
      for (int j = 0; j < 4; j++) {
        int colb = (n0 - cbase) + wn + j * 16 + l16;
        int hh = colb >> 7, d = colb & 127;
        float freq = powf(10000.0f, -(float)(d >> 1) * (1.0f / 64.0f));
#pragma unroll
        for (int i = 0; i < 4; i++) {
#pragma unroll
          for (int r = 0; r < 4; r++) {
            int row = m0 + wm + i * 16 + quad * 4 + r;
            int t = row & 1023, bb = row >> 10;
            float ang = (float)t * freq;
            float sn, cs;
            sincosf(ang, &sn, &cs);
            float own = acc[i][j][r];
            float oth = __shfl_xor(own, 1);
            float ev = par ? oth : own;
            float ov = par ? own : oth;
            float res = (par ? (ev * sn + ov * cs) : (ev * cs - ov * sn)) * scale;
            dst[((size_t)(bb * NH + hh) * 1024 + t) * 128 + d] = (bf16_t)res;
          }
        }
      }
    } else {
      // V path: write transposed [B][G][128][T]
      int bb = m0 >> 10;
#pragma unroll
      for (int j = 0; j < 4; j++) {
        int col = n0 + wn + j * 16 + l16;
        int gg = (col - 5120) >> 7, d = col & 127;
#pragma unroll
        for (int i = 0; i < 4; i++) {
          int t0 = ((m0 + wm + i * 16) & 1023) + quad * 4;
          bf16x4 v4;
#pragma unroll
          for (int r = 0; r < 4; r++) v4[r] = (bf16_t)acc[i][j][r];
          *(bf16x4*)(Vt + ((size_t)(bb * 8 + gg) * 128 + d) * 1024 + t0) = v4;
        }
      }
    }
  }
}

// ---------------- flash attention (32x32x16 MFMA, S^T formulation) ---------------
// Q [B][H][T][128] bf16 (pre-scaled by 1/sqrt(D), rope applied), K [B][G][T][128],
// V [B][G][128][T] bf16, O [B*T][H*128] bf16.
// grid 512 linear; block 256 = 4 waves; wave w owns 32 q-rows; q-tile 128, k-tile 64.
// All LDS tiles stored with XOR-swizzled 16B chunks for bank-uniform frag reads.
__global__ __launch_bounds__(256) void k_attn(
    const bf16_t* __restrict__ Q, const bf16_t* __restrict__ K,
    const bf16_t* __restrict__ V, bf16_t* __restrict__ O) {
  __shared__ __align__(16) bf16_t Qs[128 * 128];  // [q][d]   32 KB, 16-chunk rows
  __shared__ __align__(16) bf16_t Ks[64 * 128];   // [key][d] 16 KB, 16-chunk rows
  __shared__ __align__(16) bf16_t Vs[128 * 64];   // [d][key] 16 KB, 8-chunk rows
  int tid = threadIdx.x;
  int w = tid >> 6, lane = tid & 63, hi = lane >> 5, l32 = lane & 31;
  // balanced decode: CU gets blocks u and u+256 (round-robin) -> complementary tiles
  int u = blockIdx.x;
  int rr = u >> 8, s = u & 255;
  int pp0 = s & 7, h = s >> 3, b = rr;
  int tile = rr ? 7 - pp0 : pp0;
  int g = h >> 2;

  const char* Qg = (const char*)Q + ((size_t)(b * 32 + h) * 1024 + tile * 128) * 256;
  const char* Kg = (const char*)K + (size_t)(b * 8 + g) * 1024 * 256;
  const char* Vg = (const char*)V + (size_t)(b * 8 + g) * 128 * 2048;

  // stage Q (swizzled: physical chunk p holds logical chunk p^(row&15))
#pragma unroll
  for (int it = 0; it < 8; ++it) {
    int P = it * 256 + tid;
    int row = P >> 4, ph = P & 15, c = ph ^ (row & 15);
    stage16(Qg + row * 256 + c * 16, (char*)Qs + P * 16);
  }
  __syncthreads();

  bf16x8 qf[8];
#pragma unroll
  for (int kk = 0; kk < 8; ++kk) {
    int row = w * 32 + l32;
    int ph = (kk * 2 + hi) ^ (l32 & 15);
    qf[kk] = *(const bf16x8*)((const char*)Qs + row * 256 + ph * 16);
  }

  f32x16 Oacc[4] = {};
  float m_i = -INFINITY, l_i = 0.0f;
  int q0t = tile * 128 + w * 32;
  int qg = q0t + l32;
  int ktmax = 2 * tile + 1;

  for (int kt = 0; kt <= ktmax; ++kt) {
    int k0 = kt * 64;
    __syncthreads();
#pragma unroll
    for (int it = 0; it < 4; ++it) {
      int P = it * 256 + tid;
      int row = P >> 4, ph = P & 15, c = ph ^ (row & 15);
      stage16(Kg + (size_t)(k0 + row) * 256 + c * 16, (char*)Ks + P * 16);
    }
#pragma unroll
    for (int it = 0; it < 4; ++it) {
      int P = it * 256 + tid;
      int row = P >> 3, ph = P & 7, c = ph ^ (row & 7);
      stage16(Vg + (size_t)row * 2048 + k0 * 2 + c * 16, (char*)Vs + P * 16);
    }
    __syncthreads();
    if (k0 > q0t + 31) continue;  // wave fully masked this k-tile

    // S^T = K * Q^T : lane holds q=l32 (col), 16 keys per subtile (rows)
    f32x16 Sa[2];
#pragma unroll
    for (int kt2 = 0; kt2 < 2; ++kt2) {
      f32x16 sacc = {};
#pragma unroll
      for (int kk = 0; kk < 8; ++kk) {
        int row = kt2 * 32 + l32;
        int ph = (kk * 2 + hi) ^ (l32 & 15);
        bf16x8 kf = *(const bf16x8*)((const char*)Ks + row * 256 + ph * 16);
        sacc = MFMA32(kf, qf[kk], sacc);
      }
      Sa[kt2] = sacc;
    }

    // online softmax (lane-local: one q-row per lane, replicated across hi)
    float sv[32];
    float mx = -INFINITY;
#pragma unroll
    for (int kt2 = 0; kt2 < 2; ++kt2)
#pragma unroll
      for (int reg = 0; reg < 16; ++reg) {
        float v = Sa[kt2][reg];
        int key = k0 + kt2 * 32 + (reg & 3) + 8 * (reg >> 2) + 4 * hi;
        v = (key <= qg) ? v : -INFINITY;
        sv[kt2 * 16 + reg] = v;
        mx = fmaxf(mx, v);
      }
    mx = fmaxf(mx, __shfl_xor(mx, 32));
    float mn = fmaxf(m_i, mx);
    float alpha = __expf(m_i - mn);
    float sum = 0.0f;
#pragma unroll
    for (int e = 0; e < 32; ++e) {
      float pe = __expf(sv[e] - mn);
      sv[e] = pe;
      sum += pe;
    }
    sum += __shfl_xor(sum, 32);
    m_i = mn;
    l_i = l_i * alpha + sum;

    // pack P to bf16 and build A/B-operand frags via lane^32 exchange (no LDS)
    bf16x8 pf[4];
#pragma unroll
    for (int kt2 = 0; kt2 < 2; ++kt2) {
      bf16x4 pk[4];
#pragma unroll
      for (int gg = 0; gg < 4; ++gg) {
#pragma unroll
        for (int e = 0; e < 4; ++e) pk[gg][e] = (bf16_t)sv[kt2 * 16 + 4 * gg + e];
      }
      bf16x4 X = shfl_xor32_b64(hi ? pk[0] : pk[1]);
      bf16x4 Y = shfl_xor32_b64(hi ? pk[2] : pk[3]);
      pf[2 * kt2]     = (hi == 0) ? cat44(pk[0], X) : cat44(X, pk[1]);
      pf[2 * kt2 + 1] = (hi == 0) ? cat44(pk[2], Y) : cat44(Y, pk[3]);
    }

    // O^T accumulate: rescale (alpha is lane-uniform!) then O^T += V^T P^T
#pragma unroll
    for (int nt = 0; nt < 4; ++nt) {
      f32x16 o = Oacc[nt];
#pragma unroll
      for (int reg = 0; reg < 16; ++reg) o[reg] *= alpha;
#pragma unroll
      for (int kk = 0; kk < 4; ++kk) {
        int row = nt * 32 + l32;
        int ph = (kk * 2 + hi) ^ (row & 7);
        bf16x8 vf = *(const bf16x8*)((const char*)Vs + row * 128 + ph * 16);
        o = MFMA32(vf, pf[kk], o);
      }
      Oacc[nt] = o;
    }
  }

  // epilogue: lane owns q-row qg entirely; d = nt*32 + 8*gg + 4*hi + e
  float inv = 1.0f / l_i;
  bf16_t* Ob = O + ((size_t)(b * 1024 + qg)) * 4096 + h * 128;
#pragma unroll
  for (int nt = 0; nt < 4; ++nt)
#pragma unroll
    for (int gg = 0; gg < 4; ++gg) {
      bf16x4 o4;
#pragma unroll
      for (int e = 0; e < 4; ++e) o4[e] = (bf16_t)(Oacc[nt][4 * gg + e] * inv);
      *(bf16x4*)(Ob + nt * 32 + 8 * gg + 4 * hi) = o4;
    }
}

extern "C" void kernel_launch(void* const* d_in, const int* in_sizes, int n_in,
                              void* d_out, int out_size, void* d_ws, size_t ws_size,
                              hipStream_t stream) {
  const float* x  = (const float*)d_in[0];   // [2,1024,4096]
  const float* Wq = (const float*)d_in[1];   // [4096,4096]
  const float* Wk = (const float*)d_in[2];   // [4096,1024]
  const float* Wv = (const float*)d_in[3];   // [4096,1024]
  const float* Wo = (const float*)d_in[4];   // [4096,4096]
  const float* bo = (const float*)d_in[5];   // [4096]
  float* out = (float*)d_out;                // [2,1024,4096]

  char* p = (char*)d_ws;
  bf16_t* Xb    = (bf16_t*)p; p += (size_t)2048 * 4096 * 2;  // 16 MB
  bf16_t* WqkvT = (bf16_t*)p; p += (size_t)6144 * 4096 * 2;  // 48 MB
  bf16_t* WoT   = (bf16_t*)p; p += (size_t)4096 * 4096 * 2;  // 32 MB
  bf16_t* Qb    = (bf16_t*)p; p += (size_t)2048 * 4096 * 2;  // 16 MB
  bf16_t* Kb    = (bf16_t*)p; p += (size_t)2048 * 1024 * 2;  //  4 MB
  bf16_t* Vt    = (bf16_t*)p; p += (size_t)2048 * 1024 * 2;  //  4 MB
  bf16_t* Ob    = (bf16_t*)p; p += (size_t)2048 * 4096 * 2;  // 16 MB

  dim3 tb(32, 8);
  // 1. convert x to bf16
  k_convert<<<8192, 256, 0, stream>>>(x, Xb, 2048 * 4096);
  // 2. transpose weights into [N][K] bf16 (Wq/Wk/Wv concatenated)
  k_transpose<<<dim3(128, 128), tb, 0, stream>>>(Wq, WqkvT, 4096, 4096);
  k_transpose<<<dim3(32, 128),  tb, 0, stream>>>(Wk, WqkvT + (size_t)4096 * 4096, 4096, 1024);
  k_transpose<<<dim3(32, 128),  tb, 0, stream>>>(Wv, WqkvT + (size_t)5120 * 4096, 4096, 1024);
  k_transpose<<<dim3(128, 128), tb, 0, stream>>>(Wo, WoT, 4096, 4096);
  // 3. fused QKV projection + rope + layouts (single N=6144 GEMM)
  k_gemm<1><<<dim3(48, 16), 256, 0, stream>>>(Xb, WqkvT, nullptr, nullptr,
                                              Qb, Kb, Vt, 2048, 6144, 4096);
  // 4. flash attention
  k_attn<<<512, 256, 0, stream>>>(Qb, Kb, Vt, Ob);
  // 5. output projection + bias -> fp32 out
  k_gemm<0><<<dim3(32, 16), 256, 0, stream>>>(Ob, WoT, out, bo,
                                              nullptr, nullptr, nullptr, 2048, 4096, 4096);
}

// Round 3
// 507.321 us; speedup vs baseline: 4.3606x; 4.3606x over previous
//
#include <hip/hip_runtime.h>
#include <math.h>
#include <cstdint>
#include <cstddef>

// B=2, T=1024, C=4096, H=32, G=8, D=128, rep=4, M=B*T=2048
typedef __bf16 bf16_t;
typedef __bf16 bf16x8 __attribute__((ext_vector_type(8)));
typedef __bf16 bf16x4 __attribute__((ext_vector_type(4)));
typedef float f32x4 __attribute__((ext_vector_type(4)));
typedef float f32x16 __attribute__((ext_vector_type(16)));

#define MFMA16(a, b, c) __builtin_amdgcn_mfma_f32_16x16x32_bf16(a, b, c, 0, 0, 0)
#define MFMA32(a, b, c) __builtin_amdgcn_mfma_f32_32x32x16_bf16(a, b, c, 0, 0, 0)

__device__ __forceinline__ void stage16(const void* g, void* l) {
  __builtin_amdgcn_global_load_lds(
      (const __attribute__((address_space(1))) unsigned int*)g,
      (__attribute__((address_space(3))) unsigned int*)l, 16, 0, 0);
}

__device__ __forceinline__ bf16x4 shfl_xor32_b64(bf16x4 v) {
  union { bf16x4 h; unsigned int u[2]; } a;
  a.h = v;
  a.u[0] = __shfl_xor(a.u[0], 32);
  a.u[1] = __shfl_xor(a.u[1], 32);
  return a.h;
}

__device__ __forceinline__ bf16x8 cat44(bf16x4 lo, bf16x4 hiv) {
  bf16x8 r;
  r[0] = lo[0]; r[1] = lo[1]; r[2] = lo[2]; r[3] = lo[3];
  r[4] = hiv[0]; r[5] = hiv[1]; r[6] = hiv[2]; r[7] = hiv[3];
  return r;
}

// ---------------- convert fp32 -> bf16 ----------------
__global__ void k_convert(const float* __restrict__ in, bf16_t* __restrict__ out, int n) {
  int i = (blockIdx.x * blockDim.x + threadIdx.x) * 4;
  if (i >= n) return;
  float4 v = *(const float4*)(in + i);
  out[i + 0] = (bf16_t)v.x;
  out[i + 1] = (bf16_t)v.y;
  out[i + 2] = (bf16_t)v.z;
  out[i + 3] = (bf16_t)v.w;
}

// ---------------- transpose+convert: out[c][r] = in[r][c] ----------------
__global__ void k_transpose(const float* __restrict__ in, bf16_t* __restrict__ out,
                            int R, int C) {
  __shared__ float t[32][33];
  int r0 = blockIdx.y * 32, c0 = blockIdx.x * 32;
  int tx = threadIdx.x, ty = threadIdx.y;
#pragma unroll
  for (int i = 0; i < 4; i++)
    t[ty + i * 8][tx] = in[(size_t)(r0 + ty + i * 8) * C + (c0 + tx)];
  __syncthreads();
#pragma unroll
  for (int i = 0; i < 4; i++)
    out[(size_t)(c0 + ty + i * 8) * R + (r0 + tx)] = (bf16_t)t[tx][ty + i * 8];
}

// ---------------- GEMM: 128x128 tile, BK=32, m97 structure -----------------------
// MODE 0: Cout = A*BT^T + bias (fp32 out)
// MODE 1: fused QKV epilogue (NO transcendentals — spill hazard, see round 2):
//   n0<4096  -> raw Q -> Qr [B][H][T][128] bf16 (rope applied later, in-place)
//   4096..5119 -> raw K -> Kr [B][G][T][128] bf16
//   n0>=5120 -> V -> Vt [B][G][128][T] bf16 (transposed)
template <int MODE>
__global__ __launch_bounds__(256) void k_gemm(
    const bf16_t* __restrict__ A, const bf16_t* __restrict__ BT,
    float* __restrict__ Cout, const float* __restrict__ bias,
    bf16_t* __restrict__ Qr, bf16_t* __restrict__ Kr, bf16_t* __restrict__ Vt,
    int M, int N, int K) {
  __shared__ __align__(16) bf16_t As[128 * 32];
  __shared__ __align__(16) bf16_t Bs[128 * 32];
  int tid = threadIdx.x;
  int w = tid >> 6, lane = tid & 63, quad = lane >> 4, l16 = lane & 15;
  int n0 = blockIdx.x * 128, m0 = blockIdx.y * 128;
  int wm = (w >> 1) * 64, wn = (w & 1) * 64;
  const char* Ab = (const char*)A + (size_t)m0 * K * 2;
  const char* Bb = (const char*)BT + (size_t)n0 * K * 2;
  size_t rb = (size_t)K * 2;
  f32x4 acc[4][4] = {};
  for (int k0 = 0; k0 < K; k0 += 32) {
    __syncthreads();
#pragma unroll
    for (int it = 0; it < 2; ++it) {
      int off = it * 4096 + tid * 16;
      int row = off >> 6;
      int colb = off & 63;
      stage16(Ab + (size_t)row * rb + (size_t)k0 * 2 + colb, (char*)As + off);
      stage16(Bb + (size_t)row * rb + (size_t)k0 * 2 + colb, (char*)Bs + off);
    }
    __syncthreads();
    bf16x8 af[4], bfr[4];
#pragma unroll
    for (int i = 0; i < 4; i++)
      af[i] = *(const bf16x8*)&As[(wm + i * 16 + l16) * 32 + quad * 8];
#pragma unroll
    for (int j = 0; j < 4; j++)
      bfr[j] = *(const bf16x8*)&Bs[(wn + j * 16 + l16) * 32 + quad * 8];
#pragma unroll
    for (int i = 0; i < 4; i++)
#pragma unroll
      for (int j = 0; j < 4; j++)
        acc[i][j] = MFMA16(af[i], bfr[j], acc[i][j]);
  }

  if (MODE == 0) {
#pragma unroll
    for (int i = 0; i < 4; i++)
#pragma unroll
      for (int j = 0; j < 4; j++) {
        int col = n0 + wn + j * 16 + l16;
        float bv = bias[col];
#pragma unroll
        for (int r = 0; r < 4; r++) {
          int row = m0 + wm + i * 16 + quad * 4 + r;
          Cout[(size_t)row * N + col] = acc[i][j][r] + bv;
        }
      }
  } else {
#pragma unroll
    for (int j = 0; j < 4; j++) {
      int col = n0 + wn + j * 16 + l16;  // branch below is wave-uniform per j
      if (col < 5120) {
        bf16_t* dst;
        int NH, cb;
        if (col < 4096) { dst = Qr; NH = 32; cb = 0; }
        else            { dst = Kr; NH = 8;  cb = 4096; }
        int cc = col - cb, hh = cc >> 7, d = cc & 127;
#pragma unroll
        for (int i = 0; i < 4; i++)
#pragma unroll
          for (int r = 0; r < 4; r++) {
            int row = m0 + wm + i * 16 + quad * 4 + r;
            int t = row & 1023, bb = row >> 10;
            dst[((size_t)(bb * NH + hh) * 1024 + t) * 128 + d] = (bf16_t)acc[i][j][r];
          }
      } else {
        int gg = (col - 5120) >> 7, d = col & 127;
        int bb = m0 >> 10;
#pragma unroll
        for (int i = 0; i < 4; i++) {
          int t0 = ((m0 + wm + i * 16) & 1023) + quad * 4;
          bf16x4 v4;
#pragma unroll
          for (int r = 0; r < 4; r++) v4[r] = (bf16_t)acc[i][j][r];
          *(bf16x4*)(Vt + ((size_t)(bb * 8 + gg) * 128 + d) * 1024 + t0) = v4;
        }
      }
    }
  }
}

// ---------------- in-place RoPE on [B][NH][T][128] bf16 --------------------------
// Angle depends only on (t, d) — one sincosf per thread, reused over NH/4 heads.
// grid = B*T blocks; block 256 = 4 waves; wave w handles heads w*(NH/4)..+NH/4-1,
// lane handles pair d = 2*lane. Wave loads 256B contiguous per head. scale folds
// 1/sqrt(128) for Q.
__global__ __launch_bounds__(256) void k_rope(bf16_t* __restrict__ buf, int NH,
                                              float scale) {
  int bt = blockIdx.x;
  int t = bt & 1023, b = bt >> 10;
  int dp = threadIdx.x & 63;
  int h0 = threadIdx.x >> 6;
  float freq = __expf(-(float)dp * (9.210340371976184f / 64.0f));  // ln(1e4)/64
  float ang = (float)t * freq;
  float sn, cs;
  sincosf(ang, &sn, &cs);
  int hper = NH >> 2;
  for (int i = 0; i < hper; ++i) {
    int h = h0 * hper + i;
    size_t idx = ((size_t)(b * NH + h) * 1024 + t) * 128 + dp * 2;
    float xr = (float)buf[idx], xi = (float)buf[idx + 1];
    buf[idx]     = (bf16_t)((xr * cs - xi * sn) * scale);
    buf[idx + 1] = (bf16_t)((xr * sn + xi * cs) * scale);
  }
}

// ---------------- flash attention (32x32x16 MFMA, S^T formulation) ---------------
// Q [B][H][T][128] bf16 (pre-scaled, rope applied), K [B][G][T][128],
// V [B][G][128][T] bf16, O [B*T][H*128] bf16.
// grid 512 linear; block 256 = 4 waves; wave owns 32 q-rows; q-tile 128, k-tile 64.
// LDS tiles XOR-swizzled in 16B chunks for bank-uniform frag reads.
__global__ __launch_bounds__(256) void k_attn(
    const bf16_t* __restrict__ Q, const bf16_t* __restrict__ K,
    const bf16_t* __restrict__ V, bf16_t* __restrict__ O) {
  __shared__ __align__(16) bf16_t Qs[128 * 128];  // [q][d]   32 KB
  __shared__ __align__(16) bf16_t Ks[64 * 128];   // [key][d] 16 KB
  __shared__ __align__(16) bf16_t Vs[128 * 64];   // [d][key] 16 KB
  int tid = threadIdx.x;
  int w = tid >> 6, lane = tid & 63, hi = lane >> 5, l32 = lane & 31;
  int u = blockIdx.x;
  int rr = u >> 8, s = u & 255;
  int pp0 = s & 7, h = s >> 3, b = rr;
  int tile = rr ? 7 - pp0 : pp0;   // complementary causal load balance
  int g = h >> 2;

  const char* Qg = (const char*)Q + ((size_t)(b * 32 + h) * 1024 + tile * 128) * 256;
  const char* Kg = (const char*)K + (size_t)(b * 8 + g) * 1024 * 256;
  const char* Vg = (const char*)V + (size_t)(b * 8 + g) * 128 * 2048;

#pragma unroll
  for (int it = 0; it < 8; ++it) {
    int P = it * 256 + tid;
    int row = P >> 4, ph = P & 15, c = ph ^ (row & 15);
    stage16(Qg + row * 256 + c * 16, (char*)Qs + P * 16);
  }
  __syncthreads();

  bf16x8 qf[8];
#pragma unroll
  for (int kk = 0; kk < 8; ++kk) {
    int row = w * 32 + l32;
    int ph = (kk * 2 + hi) ^ (l32 & 15);
    qf[kk] = *(const bf16x8*)((const char*)Qs + row * 256 + ph * 16);
  }

  f32x16 Oacc[4] = {};
  float m_i = -INFINITY, l_i = 0.0f;
  int q0t = tile * 128 + w * 32;
  int qg = q0t + l32;
  int ktmax = 2 * tile + 1;

  for (int kt = 0; kt <= ktmax; ++kt) {
    int k0 = kt * 64;
    __syncthreads();
#pragma unroll
    for (int it = 0; it < 4; ++it) {
      int P = it * 256 + tid;
      int row = P >> 4, ph = P & 15, c = ph ^ (row & 15);
      stage16(Kg + (size_t)(k0 + row) * 256 + c * 16, (char*)Ks + P * 16);
    }
#pragma unroll
    for (int it = 0; it < 4; ++it) {
      int P = it * 256 + tid;
      int row = P >> 3, ph = P & 7, c = ph ^ (row & 7);
      stage16(Vg + (size_t)row * 2048 + k0 * 2 + c * 16, (char*)Vs + P * 16);
    }
    __syncthreads();
    if (k0 > q0t + 31) continue;  // wave fully masked this k-tile

    f32x16 Sa[2];
#pragma unroll
    for (int kt2 = 0; kt2 < 2; ++kt2) {
      f32x16 sacc = {};
#pragma unroll
      for (int kk = 0; kk < 8; ++kk) {
        int row = kt2 * 32 + l32;
        int ph = (kk * 2 + hi) ^ (l32 & 15);
        bf16x8 kf = *(const bf16x8*)((const char*)Ks + row * 256 + ph * 16);
        sacc = MFMA32(kf, qf[kk], sacc);
      }
      Sa[kt2] = sacc;
    }

    float sv[32];
    float mx = -INFINITY;
#pragma unroll
    for (int kt2 = 0; kt2 < 2; ++kt2)
#pragma unroll
      for (int reg = 0; reg < 16; ++reg) {
        float v = Sa[kt2][reg];
        int key = k0 + kt2 * 32 + (reg & 3) + 8 * (reg >> 2) + 4 * hi;
        v = (key <= qg) ? v : -INFINITY;
        sv[kt2 * 16 + reg] = v;
        mx = fmaxf(mx, v);
      }
    mx = fmaxf(mx, __shfl_xor(mx, 32));
    float mn = fmaxf(m_i, mx);
    float alpha = __expf(m_i - mn);
    float sum = 0.0f;
#pragma unroll
    for (int e = 0; e < 32; ++e) {
      float pe = __expf(sv[e] - mn);
      sv[e] = pe;
      sum += pe;
    }
    sum += __shfl_xor(sum, 32);
    m_i = mn;
    l_i = l_i * alpha + sum;

    bf16x8 pf[4];
#pragma unroll
    for (int kt2 = 0; kt2 < 2; ++kt2) {
      bf16x4 pk[4];
#pragma unroll
      for (int gg = 0; gg < 4; ++gg) {
#pragma unroll
        for (int e = 0; e < 4; ++e) pk[gg][e] = (bf16_t)sv[kt2 * 16 + 4 * gg + e];
      }
      bf16x4 X = shfl_xor32_b64(hi ? pk[0] : pk[1]);
      bf16x4 Y = shfl_xor32_b64(hi ? pk[2] : pk[3]);
      pf[2 * kt2]     = (hi == 0) ? cat44(pk[0], X) : cat44(X, pk[1]);
      pf[2 * kt2 + 1] = (hi == 0) ? cat44(pk[2], Y) : cat44(Y, pk[3]);
    }

#pragma unroll
    for (int nt = 0; nt < 4; ++nt) {
      f32x16 o = Oacc[nt];
#pragma unroll
      for (int reg = 0; reg < 16; ++reg) o[reg] *= alpha;
#pragma unroll
      for (int kk = 0; kk < 4; ++kk) {
        int row = nt * 32 + l32;
        int ph = (kk * 2 + hi) ^ (row & 7);
        bf16x8 vf = *(const bf16x8*)((const char*)Vs + row * 128 + ph * 16);
        o = MFMA32(vf, pf[kk], o);
      }
      Oacc[nt] = o;
    }
  }

  float inv = 1.0f / l_i;
  bf16_t* Ob = O + ((size_t)(b * 1024 + qg)) * 4096 + h * 128;
#pragma unroll
  for (int nt = 0; nt < 4; ++nt)
#pragma unroll
    for (int gg = 0; gg < 4; ++gg) {
      bf16x4 o4;
#pragma unroll
      for (int e = 0; e < 4; ++e) o4[e] = (bf16_t)(Oacc[nt][4 * gg + e] * inv);
      *(bf16x4*)(Ob + nt * 32 + 8 * gg + 4 * hi) = o4;
    }
}

extern "C" void kernel_launch(void* const* d_in, const int* in_sizes, int n_in,
                              void* d_out, int out_size, void* d_ws, size_t ws_size,
                              hipStream_t stream) {
  const float* x  = (const float*)d_in[0];   // [2,1024,4096]
  const float* Wq = (const float*)d_in[1];   // [4096,4096]
  const float* Wk = (const float*)d_in[2];   // [4096,1024]
  const float* Wv = (const float*)d_in[3];   // [4096,1024]
  const float* Wo = (const float*)d_in[4];   // [4096,4096]
  const float* bo = (const float*)d_in[5];   // [4096]
  float* out = (float*)d_out;                // [2,1024,4096]

  char* p = (char*)d_ws;
  bf16_t* Xb    = (bf16_t*)p; p += (size_t)2048 * 4096 * 2;  // 16 MB
  bf16_t* WqkvT = (bf16_t*)p; p += (size_t)6144 * 4096 * 2;  // 48 MB
  bf16_t* WoT   = (bf16_t*)p; p += (size_t)4096 * 4096 * 2;  // 32 MB
  bf16_t* Qb    = (bf16_t*)p; p += (size_t)2048 * 4096 * 2;  // 16 MB
  bf16_t* Kb    = (bf16_t*)p; p += (size_t)2048 * 1024 * 2;  //  4 MB
  bf16_t* Vt    = (bf16_t*)p; p += (size_t)2048 * 1024 * 2;  //  4 MB
  bf16_t* Ob    = (bf16_t*)p; p += (size_t)2048 * 4096 * 2;  // 16 MB

  dim3 tb(32, 8);
  k_convert<<<8192, 256, 0, stream>>>(x, Xb, 2048 * 4096);
  k_transpose<<<dim3(128, 128), tb, 0, stream>>>(Wq, WqkvT, 4096, 4096);
  k_transpose<<<dim3(32, 128),  tb, 0, stream>>>(Wk, WqkvT + (size_t)4096 * 4096, 4096, 1024);
  k_transpose<<<dim3(32, 128),  tb, 0, stream>>>(Wv, WqkvT + (size_t)5120 * 4096, 4096, 1024);
  k_transpose<<<dim3(128, 128), tb, 0, stream>>>(Wo, WoT, 4096, 4096);
  // fused QKV projection (raw) + permuted layouts
  k_gemm<1><<<dim3(48, 16), 256, 0, stream>>>(Xb, WqkvT, nullptr, nullptr,
                                              Qb, Kb, Vt, 2048, 6144, 4096);
  // in-place rope (Q pre-scaled by 1/sqrt(128))
  k_rope<<<2048, 256, 0, stream>>>(Qb, 32, 0.08838834764831845f);
  k_rope<<<2048, 256, 0, stream>>>(Kb, 8, 1.0f);
  k_attn<<<512, 256, 0, stream>>>(Qb, Kb, Vt, Ob);
  k_gemm<0><<<dim3(32, 16), 256, 0, stream>>>(Ob, WoT, out, bo,
                                              nullptr, nullptr, nullptr, 2048, 4096, 4096);
}

// Round 4
// 469.624 us; speedup vs baseline: 4.7106x; 1.0803x over previous
//
#include <hip/hip_runtime.h>
#include <math.h>
#include <cstdint>
#include <cstddef>

// B=2, T=1024, C=4096, H=32, G=8, D=128, rep=4, M=B*T=2048
typedef __bf16 bf16_t;
typedef __bf16 bf16x8 __attribute__((ext_vector_type(8)));
typedef __bf16 bf16x4 __attribute__((ext_vector_type(4)));
typedef float f32x4 __attribute__((ext_vector_type(4)));
typedef float f32x16 __attribute__((ext_vector_type(16)));

#define MFMA16(a, b, c) __builtin_amdgcn_mfma_f32_16x16x32_bf16(a, b, c, 0, 0, 0)
#define MFMA32(a, b, c) __builtin_amdgcn_mfma_f32_32x32x16_bf16(a, b, c, 0, 0, 0)

__device__ __forceinline__ void stage16(const void* g, void* l) {
  __builtin_amdgcn_global_load_lds(
      (const __attribute__((address_space(1))) unsigned int*)g,
      (__attribute__((address_space(3))) unsigned int*)l, 16, 0, 0);
}

__device__ __forceinline__ bf16x4 shfl_xor32_b64(bf16x4 v) {
  union { bf16x4 h; unsigned int u[2]; } a;
  a.h = v;
  a.u[0] = __shfl_xor(a.u[0], 32);
  a.u[1] = __shfl_xor(a.u[1], 32);
  return a.h;
}

__device__ __forceinline__ bf16x8 cat44(bf16x4 lo, bf16x4 hiv) {
  bf16x8 r;
  r[0] = lo[0]; r[1] = lo[1]; r[2] = lo[2]; r[3] = lo[3];
  r[4] = hiv[0]; r[5] = hiv[1]; r[6] = hiv[2]; r[7] = hiv[3];
  return r;
}

// ---------------- convert fp32 -> bf16 ----------------
__global__ void k_convert(const float* __restrict__ in, bf16_t* __restrict__ out, int n) {
  int i = (blockIdx.x * blockDim.x + threadIdx.x) * 4;
  if (i >= n) return;
  float4 v = *(const float4*)(in + i);
  out[i + 0] = (bf16_t)v.x;
  out[i + 1] = (bf16_t)v.y;
  out[i + 2] = (bf16_t)v.z;
  out[i + 3] = (bf16_t)v.w;
}

// ---------------- transpose+convert: out[c][r] = in[r][c] ----------------
__global__ void k_transpose(const float* __restrict__ in, bf16_t* __restrict__ out,
                            int R, int C) {
  __shared__ float t[32][33];
  int r0 = blockIdx.y * 32, c0 = blockIdx.x * 32;
  int tx = threadIdx.x, ty = threadIdx.y;
#pragma unroll
  for (int i = 0; i < 4; i++)
    t[ty + i * 8][tx] = in[(size_t)(r0 + ty + i * 8) * C + (c0 + tx)];
  __syncthreads();
#pragma unroll
  for (int i = 0; i < 4; i++)
    out[(size_t)(c0 + ty + i * 8) * R + (r0 + tx)] = (bf16_t)t[tx][ty + i * 8];
}

// ---------------- GEMM: 128x128 tile, BK=64, XOR-swizzled LDS --------------------
// LDS rows are 128 B = 8 chunks of 16 B; physical chunk p of row r holds logical
// chunk p^(r&7) (swizzle applied on the global address side of global_load_lds).
// Frag reads then spread all 32 banks (worst 2-way, free).
// MODE 0: Cout = A*BT^T + bias (fp32 out)
// MODE 1: fused QKV epilogue (NO transcendentals — spill hazard, round 2):
//   n0<4096 -> raw Q -> Qr [B][H][T][128]; 4096..5119 -> raw K -> Kr [B][G][T][128];
//   n0>=5120 -> V -> Vt [B][G][128][T] (transposed)
template <int MODE>
__global__ __launch_bounds__(256) void k_gemm(
    const bf16_t* __restrict__ A, const bf16_t* __restrict__ BT,
    float* __restrict__ Cout, const float* __restrict__ bias,
    bf16_t* __restrict__ Qr, bf16_t* __restrict__ Kr, bf16_t* __restrict__ Vt,
    int M, int N, int K) {
  __shared__ __align__(16) bf16_t As[128 * 64];  // 16 KB
  __shared__ __align__(16) bf16_t Bs[128 * 64];  // 16 KB
  int tid = threadIdx.x;
  int w = tid >> 6, lane = tid & 63, quad = lane >> 4, l16 = lane & 15;
  int n0 = blockIdx.x * 128, m0 = blockIdx.y * 128;
  int wm = (w >> 1) * 64, wn = (w & 1) * 64;
  const char* Ab = (const char*)A + (size_t)m0 * K * 2;
  const char* Bb = (const char*)BT + (size_t)n0 * K * 2;
  size_t rb = (size_t)K * 2;
  f32x4 acc[4][4] = {};
  for (int k0 = 0; k0 < K; k0 += 64) {
    __syncthreads();
#pragma unroll
    for (int it = 0; it < 4; ++it) {
      int P = it * 256 + tid;          // chunk-slot: 128 rows x 8 chunks
      int row = P >> 3, ph = P & 7;
      int c = ph ^ (row & 7);          // logical chunk staged into phys slot ph
      stage16(Ab + (size_t)row * rb + (size_t)k0 * 2 + c * 16, (char*)As + P * 16);
      stage16(Bb + (size_t)row * rb + (size_t)k0 * 2 + c * 16, (char*)Bs + P * 16);
    }
    __syncthreads();
#pragma unroll
    for (int ks = 0; ks < 2; ++ks) {
      bf16x8 af[4], bfr[4];
#pragma unroll
      for (int i = 0; i < 4; i++) {
        int row = wm + i * 16 + l16;
        int ph = (ks * 4 + quad) ^ (l16 & 7);
        af[i] = *(const bf16x8*)((const char*)As + row * 128 + ph * 16);
      }
#pragma unroll
      for (int j = 0; j < 4; j++) {
        int row = wn + j * 16 + l16;
        int ph = (ks * 4 + quad) ^ (l16 & 7);
        bfr[j] = *(const bf16x8*)((const char*)Bs + row * 128 + ph * 16);
      }
#pragma unroll
      for (int i = 0; i < 4; i++)
#pragma unroll
        for (int j = 0; j < 4; j++)
          acc[i][j] = MFMA16(af[i], bfr[j], acc[i][j]);
    }
  }

  if (MODE == 0) {
#pragma unroll
    for (int i = 0; i < 4; i++)
#pragma unroll
      for (int j = 0; j < 4; j++) {
        int col = n0 + wn + j * 16 + l16;
        float bv = bias[col];
#pragma unroll
        for (int r = 0; r < 4; r++) {
          int row = m0 + wm + i * 16 + quad * 4 + r;
          Cout[(size_t)row * N + col] = acc[i][j][r] + bv;
        }
      }
  } else {
#pragma unroll
    for (int j = 0; j < 4; j++) {
      int col = n0 + wn + j * 16 + l16;  // branch below is wave-uniform per j
      if (col < 5120) {
        bf16_t* dst;
        int NH, cb;
        if (col < 4096) { dst = Qr; NH = 32; cb = 0; }
        else            { dst = Kr; NH = 8;  cb = 4096; }
        int cc = col - cb, hh = cc >> 7, d = cc & 127;
#pragma unroll
        for (int i = 0; i < 4; i++)
#pragma unroll
          for (int r = 0; r < 4; r++) {
            int row = m0 + wm + i * 16 + quad * 4 + r;
            int t = row & 1023, bb = row >> 10;
            dst[((size_t)(bb * NH + hh) * 1024 + t) * 128 + d] = (bf16_t)acc[i][j][r];
          }
      } else {
        int gg = (col - 5120) >> 7, d = col & 127;
        int bb = m0 >> 10;
#pragma unroll
        for (int i = 0; i < 4; i++) {
          int t0 = ((m0 + wm + i * 16) & 1023) + quad * 4;
          bf16x4 v4;
#pragma unroll
          for (int r = 0; r < 4; r++) v4[r] = (bf16_t)acc[i][j][r];
          *(bf16x4*)(Vt + ((size_t)(bb * 8 + gg) * 128 + d) * 1024 + t0) = v4;
        }
      }
    }
  }
}

// ---------------- in-place RoPE on [B][NH][T][128] bf16 --------------------------
__global__ __launch_bounds__(256) void k_rope(bf16_t* __restrict__ buf, int NH,
                                              float scale) {
  int bt = blockIdx.x;
  int t = bt & 1023, b = bt >> 10;
  int dp = threadIdx.x & 63;
  int h0 = threadIdx.x >> 6;
  float freq = __expf(-(float)dp * (9.210340371976184f / 64.0f));  // ln(1e4)/64
  float ang = (float)t * freq;
  float sn, cs;
  sincosf(ang, &sn, &cs);
  int hper = NH >> 2;
  for (int i = 0; i < hper; ++i) {
    int h = h0 * hper + i;
    size_t idx = ((size_t)(b * NH + h) * 1024 + t) * 128 + dp * 2;
    float xr = (float)buf[idx], xi = (float)buf[idx + 1];
    buf[idx]     = (bf16_t)((xr * cs - xi * sn) * scale);
    buf[idx + 1] = (bf16_t)((xr * sn + xi * cs) * scale);
  }
}

// ---------------- flash attention (32x32x16 MFMA, S^T formulation) ---------------
__global__ __launch_bounds__(256) void k_attn(
    const bf16_t* __restrict__ Q, const bf16_t* __restrict__ K,
    const bf16_t* __restrict__ V, bf16_t* __restrict__ O) {
  __shared__ __align__(16) bf16_t Qs[128 * 128];  // [q][d]   32 KB
  __shared__ __align__(16) bf16_t Ks[64 * 128];   // [key][d] 16 KB
  __shared__ __align__(16) bf16_t Vs[128 * 64];   // [d][key] 16 KB
  int tid = threadIdx.x;
  int w = tid >> 6, lane = tid & 63, hi = lane >> 5, l32 = lane & 31;
  int u = blockIdx.x;
  int rr = u >> 8, s = u & 255;
  int pp0 = s & 7, h = s >> 3, b = rr;
  int tile = rr ? 7 - pp0 : pp0;   // complementary causal load balance
  int g = h >> 2;

  const char* Qg = (const char*)Q + ((size_t)(b * 32 + h) * 1024 + tile * 128) * 256;
  const char* Kg = (const char*)K + (size_t)(b * 8 + g) * 1024 * 256;
  const char* Vg = (const char*)V + (size_t)(b * 8 + g) * 128 * 2048;

#pragma unroll
  for (int it = 0; it < 8; ++it) {
    int P = it * 256 + tid;
    int row = P >> 4, ph = P & 15, c = ph ^ (row & 15);
    stage16(Qg + row * 256 + c * 16, (char*)Qs + P * 16);
  }
  __syncthreads();

  bf16x8 qf[8];
#pragma unroll
  for (int kk = 0; kk < 8; ++kk) {
    int row = w * 32 + l32;
    int ph = (kk * 2 + hi) ^ (l32 & 15);
    qf[kk] = *(const bf16x8*)((const char*)Qs + row * 256 + ph * 16);
  }

  f32x16 Oacc[4] = {};
  float m_i = -INFINITY, l_i = 0.0f;
  int q0t = tile * 128 + w * 32;
  int qg = q0t + l32;
  int ktmax = 2 * tile + 1;

  for (int kt = 0; kt <= ktmax; ++kt) {
    int k0 = kt * 64;
    __syncthreads();
#pragma unroll
    for (int it = 0; it < 4; ++it) {
      int P = it * 256 + tid;
      int row = P >> 4, ph = P & 15, c = ph ^ (row & 15);
      stage16(Kg + (size_t)(k0 + row) * 256 + c * 16, (char*)Ks + P * 16);
    }
#pragma unroll
    for (int it = 0; it < 4; ++it) {
      int P = it * 256 + tid;
      int row = P >> 3, ph = P & 7, c = ph ^ (row & 7);
      stage16(Vg + (size_t)row * 2048 + k0 * 2 + c * 16, (char*)Vs + P * 16);
    }
    __syncthreads();
    if (k0 > q0t + 31) continue;  // wave fully masked this k-tile

    f32x16 Sa[2];
#pragma unroll
    for (int kt2 = 0; kt2 < 2; ++kt2) {
      f32x16 sacc = {};
#pragma unroll
      for (int kk = 0; kk < 8; ++kk) {
        int row = kt2 * 32 + l32;
        int ph = (kk * 2 + hi) ^ (l32 & 15);
        bf16x8 kf = *(const bf16x8*)((const char*)Ks + row * 256 + ph * 16);
        sacc = MFMA32(kf, qf[kk], sacc);
      }
      Sa[kt2] = sacc;
    }

    float sv[32];
    float mx = -INFINITY;
#pragma unroll
    for (int kt2 = 0; kt2 < 2; ++kt2)
#pragma unroll
      for (int reg = 0; reg < 16; ++reg) {
        float v = Sa[kt2][reg];
        int key = k0 + kt2 * 32 + (reg & 3) + 8 * (reg >> 2) + 4 * hi;
        v = (key <= qg) ? v : -INFINITY;
        sv[kt2 * 16 + reg] = v;
        mx = fmaxf(mx, v);
      }
    mx = fmaxf(mx, __shfl_xor(mx, 32));
    float mn = fmaxf(m_i, mx);
    float alpha = __expf(m_i - mn);
    float sum = 0.0f;
#pragma unroll
    for (int e = 0; e < 32; ++e) {
      float pe = __expf(sv[e] - mn);
      sv[e] = pe;
      sum += pe;
    }
    sum += __shfl_xor(sum, 32);
    m_i = mn;
    l_i = l_i * alpha + sum;

    bf16x8 pf[4];
#pragma unroll
    for (int kt2 = 0; kt2 < 2; ++kt2) {
      bf16x4 pk[4];
#pragma unroll
      for (int gg = 0; gg < 4; ++gg) {
#pragma unroll
        for (int e = 0; e < 4; ++e) pk[gg][e] = (bf16_t)sv[kt2 * 16 + 4 * gg + e];
      }
      bf16x4 X = shfl_xor32_b64(hi ? pk[0] : pk[1]);
      bf16x4 Y = shfl_xor32_b64(hi ? pk[2] : pk[3]);
      pf[2 * kt2]     = (hi == 0) ? cat44(pk[0], X) : cat44(X, pk[1]);
      pf[2 * kt2 + 1] = (hi == 0) ? cat44(pk[2], Y) : cat44(Y, pk[3]);
    }

#pragma unroll
    for (int nt = 0; nt < 4; ++nt) {
      f32x16 o = Oacc[nt];
#pragma unroll
      for (int reg = 0; reg < 16; ++reg) o[reg] *= alpha;
#pragma unroll
      for (int kk = 0; kk < 4; ++kk) {
        int row = nt * 32 + l32;
        int ph = (kk * 2 + hi) ^ (row & 7);
        bf16x8 vf = *(const bf16x8*)((const char*)Vs + row * 128 + ph * 16);
        o = MFMA32(vf, pf[kk], o);
      }
      Oacc[nt] = o;
    }
  }

  float inv = 1.0f / l_i;
  bf16_t* Ob = O + ((size_t)(b * 1024 + qg)) * 4096 + h * 128;
#pragma unroll
  for (int nt = 0; nt < 4; ++nt)
#pragma unroll
    for (int gg = 0; gg < 4; ++gg) {
      bf16x4 o4;
#pragma unroll
      for (int e = 0; e < 4; ++e) o4[e] = (bf16_t)(Oacc[nt][4 * gg + e] * inv);
      *(bf16x4*)(Ob + nt * 32 + 8 * gg + 4 * hi) = o4;
    }
}

extern "C" void kernel_launch(void* const* d_in, const int* in_sizes, int n_in,
                              void* d_out, int out_size, void* d_ws, size_t ws_size,
                              hipStream_t stream) {
  const float* x  = (const float*)d_in[0];   // [2,1024,4096]
  const float* Wq = (const float*)d_in[1];   // [4096,4096]
  const float* Wk = (const float*)d_in[2];   // [4096,1024]
  const float* Wv = (const float*)d_in[3];   // [4096,1024]
  const float* Wo = (const float*)d_in[4];   // [4096,4096]
  const float* bo = (const float*)d_in[5];   // [4096]
  float* out = (float*)d_out;                // [2,1024,4096]

  char* p = (char*)d_ws;
  bf16_t* Xb    = (bf16_t*)p; p += (size_t)2048 * 4096 * 2;  // 16 MB
  bf16_t* WqkvT = (bf16_t*)p; p += (size_t)6144 * 4096 * 2;  // 48 MB
  bf16_t* WoT   = (bf16_t*)p; p += (size_t)4096 * 4096 * 2;  // 32 MB
  bf16_t* Qb    = (bf16_t*)p; p += (size_t)2048 * 4096 * 2;  // 16 MB
  bf16_t* Kb    = (bf16_t*)p; p += (size_t)2048 * 1024 * 2;  //  4 MB
  bf16_t* Vt    = (bf16_t*)p; p += (size_t)2048 * 1024 * 2;  //  4 MB
  bf16_t* Ob    = (bf16_t*)p; p += (size_t)2048 * 4096 * 2;  // 16 MB

  dim3 tb(32, 8);
  k_convert<<<8192, 256, 0, stream>>>(x, Xb, 2048 * 4096);
  k_transpose<<<dim3(128, 128), tb, 0, stream>>>(Wq, WqkvT, 4096, 4096);
  k_transpose<<<dim3(32, 128),  tb, 0, stream>>>(Wk, WqkvT + (size_t)4096 * 4096, 4096, 1024);
  k_transpose<<<dim3(32, 128),  tb, 0, stream>>>(Wv, WqkvT + (size_t)5120 * 4096, 4096, 1024);
  k_transpose<<<dim3(128, 128), tb, 0, stream>>>(Wo, WoT, 4096, 4096);
  // fused QKV projection (raw) + permuted layouts
  k_gemm<1><<<dim3(48, 16), 256, 0, stream>>>(Xb, WqkvT, nullptr, nullptr,
                                              Qb, Kb, Vt, 2048, 6144, 4096);
  // in-place rope (Q pre-scaled by 1/sqrt(128))
  k_rope<<<2048, 256, 0, stream>>>(Qb, 32, 0.08838834764831845f);
  k_rope<<<2048, 256, 0, stream>>>(Kb, 8, 1.0f);
  k_attn<<<512, 256, 0, stream>>>(Qb, Kb, Vt, Ob);
  k_gemm<0><<<dim3(32, 16), 256, 0, stream>>>(Ob, WoT, out, bo,
                                              nullptr, nullptr, nullptr, 2048, 4096, 4096);
}